// Round 2
// baseline (2029.061 us; speedup 1.0000x reference)
//
#include <hip/hip_runtime.h>
#include <math.h>

#define N_ENT 200000
#define N_USERS 100000
#define N_FACTORS 4
#define NREL1 25           // N_REL - 1
#define CH 64
#define N_EDGES 1000000
#define NNZ 1000000

// 1 / (2*sqrt(32))
#define SCORE_SCALE 0.08838834764831845f

// ---- tiny precompute: Mvec[r] = (W W^T) weight[r]; wnorm[r]; disen[f][c] ----
__global__ void precompute_k(const float* __restrict__ W,       // [64,64]
                             const float* __restrict__ weight,  // [25,64]
                             const float* __restrict__ datt,    // [4,25]
                             float* __restrict__ Mvec,          // [25,64]
                             float* __restrict__ wnorm,         // [25]
                             float* __restrict__ disen) {       // [4,64]
    __shared__ float sW[64 * 64];
    __shared__ float sw[NREL1 * 64];
    __shared__ float sWWt[64 * 64];
    int tid = threadIdx.x;
    for (int i = tid; i < 64 * 64; i += 256) sW[i] = W[i];
    for (int i = tid; i < NREL1 * 64; i += 256) sw[i] = weight[i];
    __syncthreads();
    for (int e = tid; e < 64 * 64; e += 256) {
        int i = e >> 6, j = e & 63;
        float s = 0.f;
        for (int k = 0; k < 64; ++k) s += sW[i * 64 + k] * sW[j * 64 + k];
        sWWt[e] = s;
    }
    __syncthreads();
    for (int e = tid; e < NREL1 * 64; e += 256) {
        int r = e >> 6, i = e & 63;
        float s = 0.f;
        for (int j = 0; j < 64; ++j) s += sWWt[i * 64 + j] * sw[r * 64 + j];
        Mvec[e] = s;
    }
    for (int r = tid; r < NREL1; r += 256) {
        float s = 0.f;
        for (int j = 0; j < 64; ++j) { float v = sw[r * 64 + j]; s += v * v; }
        wnorm[r] = s;
    }
    for (int e = tid; e < N_FACTORS * 64; e += 256) {
        int f = e >> 6, c = e & 63;
        float m = -1e30f;
        for (int r = 0; r < NREL1; ++r) m = fmaxf(m, datt[f * NREL1 + r]);
        float ssum = 0.f, acc = 0.f;
        for (int r = 0; r < NREL1; ++r) {
            float p = expf(datt[f * NREL1 + r] - m);
            ssum += p;
            acc += p * sw[r * 64 + c];
        }
        disen[e] = acc / ssum;
    }
}

// ---- S-table: E[i][r] = exp(scale * dot(ent[i], Mvec[r])), sequential ent read ----
__global__ void s_table_k(const float* __restrict__ ent,
                          const float* __restrict__ Mvec,
                          float* __restrict__ E) {
    __shared__ float4 sM[NREL1 * 16];
    int tid = threadIdx.x;
    for (int i = tid; i < NREL1 * 16; i += 256) sM[i] = ((const float4*)Mvec)[i];
    __syncthreads();
    int gid = blockIdx.x * 256 + tid;
    int i = gid >> 4;
    int sub = tid & 15;
    if (i >= N_ENT) return;
    float4 v = ((const float4*)ent)[i * 16 + sub];
    float e0 = 0.f, e1 = 0.f;
    for (int r = 0; r < NREL1; ++r) {
        float4 m = sM[r * 16 + sub];
        float d = v.x * m.x + v.y * m.y + v.z * m.z + v.w * m.w;
        d += __shfl_xor(d, 1);
        d += __shfl_xor(d, 2);
        d += __shfl_xor(d, 4);
        d += __shfl_xor(d, 8);
        float ex = __expf(d * SCORE_SCALE);
        if ((r & 15) == sub) { if (r < 16) e0 = ex; else e1 = ex; }
    }
    E[i * NREL1 + sub] = e0;
    if (sub + 16 < NREL1) E[i * NREL1 + sub + 16] = e1;
}

// ---- Pass 1a (table path): er = E[h][r]; edge_buf=er; denom_r+=er; cnt+=1 ----
__global__ void p1_table(const int* __restrict__ head,
                         const int* __restrict__ etype,
                         const float* __restrict__ E,
                         float* __restrict__ edge_buf,
                         float* __restrict__ denom_r,
                         unsigned* __restrict__ cnt) {
    int e = blockIdx.x * blockDim.x + threadIdx.x;
    if (e >= N_EDGES) return;
    int h = head[e];
    int r = etype[e] - 1;
    float er = E[h * NREL1 + r];
    edge_buf[e] = er;
    atomicAdd(&denom_r[h], er);
    atomicAdd(&cnt[h], 1u);
}

// ---- Pass 1b (fallback, no table): per-edge dot with Mvec ----
__global__ void p1_direct(const float* __restrict__ ent,
                          const int* __restrict__ head,
                          const int* __restrict__ etype,
                          const float* __restrict__ Mvec,
                          float* __restrict__ edge_buf,
                          float* __restrict__ denom_r,
                          unsigned* __restrict__ cnt) {
    __shared__ float4 sM[NREL1 * 16];
    int tid = threadIdx.x;
    for (int i = tid; i < NREL1 * 16; i += 256) sM[i] = ((const float4*)Mvec)[i];
    __syncthreads();
    int gid = blockIdx.x * 256 + tid;
    int e = gid >> 4;
    int sub = tid & 15;
    if (e >= N_EDGES) return;
    int h = head[e];
    int r = etype[e] - 1;
    float4 v = ((const float4*)ent)[h * 16 + sub];
    float4 m = sM[r * 16 + sub];
    float d = v.x * m.x + v.y * m.y + v.z * m.z + v.w * m.w;
    d += __shfl_xor(d, 1);
    d += __shfl_xor(d, 2);
    d += __shfl_xor(d, 4);
    d += __shfl_xor(d, 8);
    if (sub == 0) {
        float er = __expf(d * SCORE_SCALE);
        edge_buf[e] = er;
        atomicAdd(&denom_r[h], er);
        atomicAdd(&cnt[h], 1u);
    }
}

// ---- Pass 2: trip = dot(h,t) + ra^2*wnorm[r]; et=exp(trip); denom_t+=et ----
__global__ void p2_trip(const float* __restrict__ ent,
                        const int* __restrict__ head,
                        const int* __restrict__ tail,
                        const int* __restrict__ etype,
                        const float* __restrict__ denom_r,
                        const float* __restrict__ wnorm,
                        float* __restrict__ edge_buf,
                        float* __restrict__ denom_t) {
    int gid = blockIdx.x * 256 + threadIdx.x;
    int e = gid >> 4;
    int sub = threadIdx.x & 15;
    if (e >= N_EDGES) return;
    int h = head[e];
    int t = tail[e];
    const float4* e4 = (const float4*)ent;
    float4 hv = e4[h * 16 + sub];
    float4 tv = e4[t * 16 + sub];
    float d = hv.x * tv.x + hv.y * tv.y + hv.z * tv.z + hv.w * tv.w;
    d += __shfl_xor(d, 1);
    d += __shfl_xor(d, 2);
    d += __shfl_xor(d, 4);
    d += __shfl_xor(d, 8);
    if (sub == 0) {
        int r = etype[e] - 1;
        float ra = edge_buf[e] / denom_r[h];
        float et = __expf(d + ra * ra * wnorm[r]);
        edge_buf[e] = et;
        atomicAdd(&denom_t[h], et);
    }
}

// ---- Pass 3: out[h] += ent[t]*weight[r]*(et/denom_t[h]) ----
__global__ void p3_agg(const float* __restrict__ ent,
                       const float* __restrict__ weight,
                       const int* __restrict__ head,
                       const int* __restrict__ tail,
                       const int* __restrict__ etype,
                       const float* __restrict__ denom_t,
                       const float* __restrict__ edge_buf,
                       float* __restrict__ out) {
    int gid = blockIdx.x * 256 + threadIdx.x;
    int e = gid >> 4;
    int sub = threadIdx.x & 15;
    if (e >= N_EDGES) return;
    int h = head[e];
    int t = tail[e];
    int r = etype[e] - 1;
    float mask = edge_buf[e] / denom_t[h];
    float4 tv = ((const float4*)ent)[t * 16 + sub];
    float4 wv = ((const float4*)weight)[r * 16 + sub];
    float* o = out + (size_t)h * 64 + sub * 4;
    atomicAdd(o + 0, tv.x * wv.x * mask);
    atomicAdd(o + 1, tv.y * wv.y * mask);
    atomicAdd(o + 2, tv.z * wv.z * mask);
    atomicAdd(o + 3, tv.w * wv.w * mask);
}

// ---- P6: out[h][c] /= max(cnt[h],1), float4 ----
__global__ void p6_fin(float* __restrict__ out, const unsigned* __restrict__ cnt) {
    int idx = blockIdx.x * blockDim.x + threadIdx.x;
    if (idx >= N_ENT * 16) return;
    float inv = 1.0f / fmaxf((float)cnt[idx >> 4], 1.0f);
    float4 v = ((float4*)out)[idx];
    v.x *= inv; v.y *= inv; v.z *= inv; v.w *= inv;
    ((float4*)out)[idx] = v;
}

// ---- U1: out_user[row] += ent[col] * val ----
__global__ void u1_agg(const float* __restrict__ ent,
                       const int* __restrict__ rows,
                       const int* __restrict__ cols,
                       const float* __restrict__ vals,
                       float* __restrict__ out_user) {
    int gid = blockIdx.x * 256 + threadIdx.x;
    int i = gid >> 4;
    int sub = threadIdx.x & 15;
    if (i >= NNZ) return;
    int u = rows[i];
    int c = cols[i];
    float val = vals[i];
    float4 v = ((const float4*)ent)[c * 16 + sub];
    float* o = out_user + (size_t)u * 64 + sub * 4;
    atomicAdd(o + 0, v.x * val);
    atomicAdd(o + 1, v.y * val);
    atomicAdd(o + 2, v.z * val);
    atomicAdd(o + 3, v.w * val);
}

// ---- U2: out_user[u] *= (1 + softmax(uemb@lat^T) @ disen) ----
__global__ void u2_fin(const float* __restrict__ uemb,
                       const float* __restrict__ lat,     // [4,64]
                       const float* __restrict__ disen,   // [4,64]
                       float* __restrict__ out_user) {
    int gid = blockIdx.x * 256 + threadIdx.x;
    int u = gid >> 4;
    int sub = threadIdx.x & 15;
    if (u >= N_USERS) return;
    float4 uv = ((const float4*)uemb)[u * 16 + sub];
    float d[N_FACTORS];
    for (int f = 0; f < N_FACTORS; ++f) {
        float4 lv = ((const float4*)lat)[f * 16 + sub];
        float v = uv.x * lv.x + uv.y * lv.y + uv.z * lv.z + uv.w * lv.w;
        v += __shfl_xor(v, 1);
        v += __shfl_xor(v, 2);
        v += __shfl_xor(v, 4);
        v += __shfl_xor(v, 8);
        d[f] = v;
    }
    float m = fmaxf(fmaxf(d[0], d[1]), fmaxf(d[2], d[3]));
    float s = 0.f;
    float p[N_FACTORS];
    for (int f = 0; f < N_FACTORS; ++f) { p[f] = __expf(d[f] - m); s += p[f]; }
    float inv = 1.0f / s;
    float4 g = make_float4(0.f, 0.f, 0.f, 0.f);
    for (int f = 0; f < N_FACTORS; ++f) {
        float4 dv = ((const float4*)disen)[f * 16 + sub];
        float w = p[f] * inv;
        g.x += w * dv.x; g.y += w * dv.y; g.z += w * dv.z; g.w += w * dv.w;
    }
    float4* o4 = (float4*)(out_user + (size_t)u * 64) + sub;
    float4 v = *o4;
    v.x *= (1.0f + g.x); v.y *= (1.0f + g.y); v.z *= (1.0f + g.z); v.w *= (1.0f + g.w);
    *o4 = v;
}

extern "C" void kernel_launch(void* const* d_in, const int* in_sizes, int n_in,
                              void* d_out, int out_size, void* d_ws, size_t ws_size,
                              hipStream_t stream) {
    (void)in_sizes; (void)n_in; (void)out_size;
    const float* ent    = (const float*)d_in[0];
    const float* uemb   = (const float*)d_in[1];
    const float* lat    = (const float*)d_in[2];
    const int*   eidx   = (const int*)d_in[3];
    const int*   etype  = (const int*)d_in[4];
    const int*   urows  = (const int*)d_in[5];
    const int*   ucols  = (const int*)d_in[6];
    const float* uvals  = (const float*)d_in[7];
    const float* weight = (const float*)d_in[8];
    const float* datt   = (const float*)d_in[9];
    const float* W      = (const float*)d_in[10];

    const int* head = eidx;
    const int* tail = eidx + N_EDGES;
    float* out = (float*)d_out;
    float* out_user = out + (size_t)N_ENT * 64;

    // ws layout (floats): denom_r[200k] denom_t[200k] cnt[200k] edge_buf[1M]
    //                     Mvec[1600] wnorm[32] disen[256] E[5M]
    float*    denom_r  = (float*)d_ws;
    float*    denom_t  = denom_r + N_ENT;
    unsigned* cnt      = (unsigned*)(denom_t + N_ENT);
    float*    edge_buf = (float*)(cnt + N_ENT);
    float*    Mvec     = edge_buf + N_EDGES;
    float*    wnorm    = Mvec + NREL1 * 64;
    float*    disen    = wnorm + 32;
    float*    E        = disen + N_FACTORS * 64;

    size_t need_with_E = (size_t)(3 * N_ENT + N_EDGES + NREL1 * 64 + 32 +
                                  N_FACTORS * 64 + (size_t)N_ENT * NREL1) * 4;
    bool use_table = ws_size >= need_with_E;

    hipMemsetAsync(d_out, 0, (size_t)(N_ENT + N_USERS) * 64 * sizeof(float), stream);
    hipMemsetAsync(d_ws, 0, (size_t)3 * N_ENT * sizeof(float), stream);

    precompute_k<<<1, 256, 0, stream>>>(W, weight, datt, Mvec, wnorm, disen);

    const int BLK = 256;
    int gridE16 = (N_EDGES * 16 + BLK - 1) / BLK;   // 16 lanes per edge

    if (use_table) {
        s_table_k<<<(N_ENT * 16 + BLK - 1) / BLK, BLK, 0, stream>>>(ent, Mvec, E);
        p1_table<<<(N_EDGES + BLK - 1) / BLK, BLK, 0, stream>>>(head, etype, E,
                                                                edge_buf, denom_r, cnt);
    } else {
        p1_direct<<<gridE16, BLK, 0, stream>>>(ent, head, etype, Mvec,
                                               edge_buf, denom_r, cnt);
    }

    p2_trip<<<gridE16, BLK, 0, stream>>>(ent, head, tail, etype, denom_r, wnorm,
                                         edge_buf, denom_t);
    p3_agg<<<gridE16, BLK, 0, stream>>>(ent, weight, head, tail, etype, denom_t,
                                        edge_buf, out);
    p6_fin<<<(N_ENT * 16 + BLK - 1) / BLK, BLK, 0, stream>>>(out, cnt);
    u1_agg<<<(NNZ * 16 + BLK - 1) / BLK, BLK, 0, stream>>>(ent, urows, ucols, uvals, out_user);
    u2_fin<<<(N_USERS * 16 + BLK - 1) / BLK, BLK, 0, stream>>>(uemb, lat, disen, out_user);
}

// Round 3
// 442.856 us; speedup vs baseline: 4.5818x; 4.5818x over previous
//
#include <hip/hip_runtime.h>
#include <math.h>

#define N_ENT 200000
#define N_USERS 100000
#define N_FACTORS 4
#define NREL1 25           // N_REL - 1
#define CH 64
#define N_EDGES 1000000
#define NNZ 1000000

// 1 / (2*sqrt(32))
#define SCORE_SCALE 0.08838834764831845f

__device__ __forceinline__ float red16(float d) {
    d += __shfl_xor(d, 1);
    d += __shfl_xor(d, 2);
    d += __shfl_xor(d, 4);
    d += __shfl_xor(d, 8);
    return d;
}
__device__ __forceinline__ float dot4(float4 a, float4 b) {
    return a.x * b.x + a.y * b.y + a.z * b.z + a.w * b.w;
}

// ---- tiny precompute: Mvec[r] = (W W^T) weight[r]; wnorm[r]; disen[f][c] ----
__global__ void precompute_k(const float* __restrict__ W,       // [64,64]
                             const float* __restrict__ weight,  // [25,64]
                             const float* __restrict__ datt,    // [4,25]
                             float* __restrict__ Mvec,          // [25,64]
                             float* __restrict__ wnorm,         // [25]
                             float* __restrict__ disen) {       // [4,64]
    __shared__ float sW[64 * 64];
    __shared__ float sw[NREL1 * 64];
    __shared__ float sWWt[64 * 64];
    int tid = threadIdx.x;
    for (int i = tid; i < 64 * 64; i += 256) sW[i] = W[i];
    for (int i = tid; i < NREL1 * 64; i += 256) sw[i] = weight[i];
    __syncthreads();
    for (int e = tid; e < 64 * 64; e += 256) {
        int i = e >> 6, j = e & 63;
        float s = 0.f;
        for (int k = 0; k < 64; ++k) s += sW[i * 64 + k] * sW[j * 64 + k];
        sWWt[e] = s;
    }
    __syncthreads();
    for (int e = tid; e < NREL1 * 64; e += 256) {
        int r = e >> 6, i = e & 63;
        float s = 0.f;
        for (int j = 0; j < 64; ++j) s += sWWt[i * 64 + j] * sw[r * 64 + j];
        Mvec[e] = s;
    }
    for (int r = tid; r < NREL1; r += 256) {
        float s = 0.f;
        for (int j = 0; j < 64; ++j) { float v = sw[r * 64 + j]; s += v * v; }
        wnorm[r] = s;
    }
    for (int e = tid; e < N_FACTORS * 64; e += 256) {
        int f = e >> 6, c = e & 63;
        float m = -1e30f;
        for (int r = 0; r < NREL1; ++r) m = fmaxf(m, datt[f * NREL1 + r]);
        float ssum = 0.f, acc = 0.f;
        for (int r = 0; r < NREL1; ++r) {
            float p = expf(datt[f * NREL1 + r] - m);
            ssum += p;
            acc += p * sw[r * 64 + c];
        }
        disen[e] = acc / ssum;
    }
}

// ---- count: degree of each head / each user row (4B atomics, L2-local) ----
__global__ void count_k(const int* __restrict__ head,
                        const int* __restrict__ rows,
                        unsigned* __restrict__ cnt_e,
                        unsigned* __restrict__ cnt_u) {
    int i = blockIdx.x * 256 + threadIdx.x;
    if (i < N_EDGES) {
        atomicAdd(&cnt_e[head[i]], 1u);
    } else {
        int j = i - N_EDGES;
        if (j < NNZ) atomicAdd(&cnt_u[rows[j]], 1u);
    }
}

// ---- scan step 1: per-256-block sums ----
__global__ void block_sums_k(const unsigned* __restrict__ cnt,
                             unsigned* __restrict__ partial, int n) {
    int i = blockIdx.x * 256 + threadIdx.x;
    unsigned v = (i < n) ? cnt[i] : 0u;
    for (int o = 32; o; o >>= 1) v += __shfl_down(v, o);
    __shared__ unsigned ws[4];
    if ((threadIdx.x & 63) == 0) ws[threadIdx.x >> 6] = v;
    __syncthreads();
    if (threadIdx.x == 0)
        partial[blockIdx.x] = ws[0] + ws[1] + ws[2] + ws[3];
}

// ---- scan step 2: single block, exclusive-scan both partial arrays in place ----
__global__ void scan_partials_k(unsigned* __restrict__ pe, int ne,
                                unsigned* __restrict__ pu, int nu) {
    __shared__ unsigned s[1024];
    int tid = threadIdx.x;
    unsigned v = (tid < ne) ? pe[tid] : 0u;
    s[tid] = v; __syncthreads();
    for (int o = 1; o < 1024; o <<= 1) {
        unsigned t = (tid >= o) ? s[tid - o] : 0u;
        __syncthreads();
        s[tid] += t;
        __syncthreads();
    }
    if (tid < ne) pe[tid] = s[tid] - v;
    __syncthreads();
    unsigned v2 = (tid < nu) ? pu[tid] : 0u;
    s[tid] = v2; __syncthreads();
    for (int o = 1; o < 1024; o <<= 1) {
        unsigned t = (tid >= o) ? s[tid - o] : 0u;
        __syncthreads();
        s[tid] += t;
        __syncthreads();
    }
    if (tid < nu) pu[tid] = s[tid] - v2;
}

// ---- scan step 3: emit offsets; cnt becomes the fill cursor (aliased) ----
__global__ void scan_emit_k(unsigned* cnt,                 // aliased w/ cursor
                            const unsigned* __restrict__ blockbase,
                            unsigned* __restrict__ offs, int n) {
    __shared__ unsigned s[256];
    int tid = threadIdx.x;
    int i = blockIdx.x * 256 + tid;
    unsigned v = (i < n) ? cnt[i] : 0u;
    s[tid] = v; __syncthreads();
    for (int o = 1; o < 256; o <<= 1) {
        unsigned t = (tid >= o) ? s[tid - o] : 0u;
        __syncthreads();
        s[tid] += t;
        __syncthreads();
    }
    unsigned incl = s[tid];
    unsigned excl = incl - v;
    unsigned base = blockbase[blockIdx.x];
    if (i < n) {
        offs[i] = base + excl;
        cnt[i] = base + excl;           // cursor init
        if (i == n - 1) offs[n] = base + incl;
    }
}

// ---- fill: scatter packed CSR records (tail|rel<<18) / (col,val) ----
__global__ void fill_k(const int* __restrict__ head,
                       const int* __restrict__ tail,
                       const int* __restrict__ etype,
                       const int* __restrict__ rows,
                       const int* __restrict__ cols,
                       const float* __restrict__ vals,
                       unsigned* cur_e, unsigned* cur_u,
                       unsigned* __restrict__ csr_e,
                       int* __restrict__ csr_c,
                       float* __restrict__ csr_v) {
    int i = blockIdx.x * 256 + threadIdx.x;
    if (i < N_EDGES) {
        int h = head[i];
        unsigned pos = atomicAdd(&cur_e[h], 1u);
        csr_e[pos] = (unsigned)tail[i] | ((unsigned)(etype[i] - 1) << 18);
    } else {
        int j = i - N_EDGES;
        if (j < NNZ) {
            int u = rows[j];
            unsigned pos = atomicAdd(&cur_u[u], 1u);
            csr_c[pos] = cols[j];
            csr_v[pos] = vals[j];
        }
    }
}

// ---- entity gather: per head, two passes over its CSR segment ----
// out[h] = (sum_e et*ent[t]*w[r]) / (sum_e et) / deg
// where et = exp(dot(h,t) + ra^2*wnorm[r]), ra = er/denom_r, er = exp(scale*dot(h,Mvec[r]))
__global__ void ent_gather_k(const float* __restrict__ ent,
                             const float* __restrict__ weight,
                             const float* __restrict__ Mvec,
                             const float* __restrict__ wnorm,
                             const unsigned* __restrict__ offs,
                             const unsigned* __restrict__ csr_e,
                             float* __restrict__ out) {
    int gid = blockIdx.x * 256 + threadIdx.x;
    int h = gid >> 4;
    int sub = threadIdx.x & 15;
    if (h >= N_ENT) return;
    int beg = offs[h], end = offs[h + 1];
    const float4* e4 = (const float4*)ent;
    float4* o4 = (float4*)out;
    if (beg == end) {                       // deg 0: emit zeros (no memset pass)
        o4[h * 16 + sub] = make_float4(0.f, 0.f, 0.f, 0.f);
        return;
    }
    float4 hv = e4[h * 16 + sub];
    // pass 1: denom_r
    float dr = 0.f;
    for (int i = beg; i < end; ++i) {
        unsigned p = csr_e[i];
        int r = p >> 18;
        float d = red16(dot4(hv, ((const float4*)Mvec)[r * 16 + sub]));
        dr += __expf(d * SCORE_SCALE);
    }
    float inv_dr = 1.0f / dr;
    // pass 2: numerator + denom_t
    float4 acc = make_float4(0.f, 0.f, 0.f, 0.f);
    float dt = 0.f;
    for (int i = beg; i < end; ++i) {
        unsigned p = csr_e[i];
        int t = p & 0x3FFFF;
        int r = p >> 18;
        float d1 = red16(dot4(hv, ((const float4*)Mvec)[r * 16 + sub]));
        float er = __expf(d1 * SCORE_SCALE);
        float ra = er * inv_dr;
        float4 tv = e4[t * 16 + sub];
        float d2 = red16(dot4(hv, tv));
        float et = __expf(d2 + ra * ra * wnorm[r]);
        dt += et;
        float4 wv = ((const float4*)weight)[r * 16 + sub];
        acc.x += et * tv.x * wv.x;
        acc.y += et * tv.y * wv.y;
        acc.z += et * tv.z * wv.z;
        acc.w += et * tv.w * wv.w;
    }
    float inv = 1.0f / (dt * (float)(end - beg));
    acc.x *= inv; acc.y *= inv; acc.z *= inv; acc.w *= inv;
    o4[h * 16 + sub] = acc;
}

// ---- user gather + fused softmax scaling epilogue ----
__global__ void user_gather_k(const float* __restrict__ ent,
                              const float* __restrict__ uemb,
                              const float* __restrict__ lat,    // [4,64]
                              const float* __restrict__ disen,  // [4,64]
                              const unsigned* __restrict__ offs,
                              const int* __restrict__ csr_c,
                              const float* __restrict__ csr_v,
                              float* __restrict__ out_user) {
    int gid = blockIdx.x * 256 + threadIdx.x;
    int u = gid >> 4;
    int sub = threadIdx.x & 15;
    if (u >= N_USERS) return;
    int beg = offs[u], end = offs[u + 1];
    const float4* e4 = (const float4*)ent;
    float4 acc = make_float4(0.f, 0.f, 0.f, 0.f);
    for (int i = beg; i < end; ++i) {
        int c = csr_c[i];
        float v = csr_v[i];
        float4 cv = e4[c * 16 + sub];
        acc.x += v * cv.x; acc.y += v * cv.y; acc.z += v * cv.z; acc.w += v * cv.w;
    }
    // epilogue: *(1 + softmax(uemb@lat^T) @ disen)
    float4 uv = ((const float4*)uemb)[u * 16 + sub];
    float d[N_FACTORS];
    for (int f = 0; f < N_FACTORS; ++f)
        d[f] = red16(dot4(uv, ((const float4*)lat)[f * 16 + sub]));
    float m = fmaxf(fmaxf(d[0], d[1]), fmaxf(d[2], d[3]));
    float s = 0.f, p[N_FACTORS];
    for (int f = 0; f < N_FACTORS; ++f) { p[f] = __expf(d[f] - m); s += p[f]; }
    float invs = 1.0f / s;
    float4 g = make_float4(0.f, 0.f, 0.f, 0.f);
    for (int f = 0; f < N_FACTORS; ++f) {
        float w = p[f] * invs;
        float4 dv = ((const float4*)disen)[f * 16 + sub];
        g.x += w * dv.x; g.y += w * dv.y; g.z += w * dv.z; g.w += w * dv.w;
    }
    acc.x *= (1.0f + g.x); acc.y *= (1.0f + g.y);
    acc.z *= (1.0f + g.z); acc.w *= (1.0f + g.w);
    ((float4*)out_user)[u * 16 + sub] = acc;
}

extern "C" void kernel_launch(void* const* d_in, const int* in_sizes, int n_in,
                              void* d_out, int out_size, void* d_ws, size_t ws_size,
                              hipStream_t stream) {
    (void)in_sizes; (void)n_in; (void)out_size; (void)ws_size;
    const float* ent    = (const float*)d_in[0];
    const float* uemb   = (const float*)d_in[1];
    const float* lat    = (const float*)d_in[2];
    const int*   eidx   = (const int*)d_in[3];
    const int*   etype  = (const int*)d_in[4];
    const int*   urows  = (const int*)d_in[5];
    const int*   ucols  = (const int*)d_in[6];
    const float* uvals  = (const float*)d_in[7];
    const float* weight = (const float*)d_in[8];
    const float* datt   = (const float*)d_in[9];
    const float* W      = (const float*)d_in[10];

    const int* head = eidx;
    const int* tail = eidx + N_EDGES;
    float* out = (float*)d_out;
    float* out_user = out + (size_t)N_ENT * 64;

    // ws layout (4B words), ~14.4 MB total
    unsigned* cnt_e  = (unsigned*)d_ws;            // 200000 (becomes cursor)
    unsigned* cnt_u  = cnt_e + N_ENT;              // 100000 (becomes cursor)
    unsigned* offs_e = cnt_u + N_USERS;            // 200001
    unsigned* offs_u = offs_e + (N_ENT + 1);       // 100001
    unsigned* pe     = offs_u + (N_USERS + 1);     // 1024 block partials (ent)
    unsigned* pu     = pe + 1024;                  // 1024 block partials (user)
    unsigned* csr_e  = pu + 1024;                  // 1M packed (tail|rel<<18)
    int*      csr_c  = (int*)(csr_e + N_EDGES);    // 1M
    float*    csr_v  = (float*)(csr_c + NNZ);      // 1M
    float*    Mvec   = csr_v + NNZ;                // 1600
    float*    wnorm  = Mvec + NREL1 * 64;          // 32
    float*    disen  = wnorm + 32;                 // 256

    const int BLK = 256;
    const int NBLK_E = (N_ENT + BLK - 1) / BLK;      // 782
    const int NBLK_U = (N_USERS + BLK - 1) / BLK;    // 391
    const int NTOT = N_EDGES + NNZ;

    hipMemsetAsync(d_ws, 0, (size_t)(N_ENT + N_USERS) * 4, stream);

    precompute_k<<<1, 256, 0, stream>>>(W, weight, datt, Mvec, wnorm, disen);
    count_k<<<(NTOT + BLK - 1) / BLK, BLK, 0, stream>>>(head, urows, cnt_e, cnt_u);
    block_sums_k<<<NBLK_E, BLK, 0, stream>>>(cnt_e, pe, N_ENT);
    block_sums_k<<<NBLK_U, BLK, 0, stream>>>(cnt_u, pu, N_USERS);
    scan_partials_k<<<1, 1024, 0, stream>>>(pe, NBLK_E, pu, NBLK_U);
    scan_emit_k<<<NBLK_E, BLK, 0, stream>>>(cnt_e, pe, offs_e, N_ENT);
    scan_emit_k<<<NBLK_U, BLK, 0, stream>>>(cnt_u, pu, offs_u, N_USERS);
    fill_k<<<(NTOT + BLK - 1) / BLK, BLK, 0, stream>>>(head, tail, etype,
                                                       urows, ucols, uvals,
                                                       cnt_e, cnt_u,
                                                       csr_e, csr_c, csr_v);
    ent_gather_k<<<(N_ENT * 16 + BLK - 1) / BLK, BLK, 0, stream>>>(
        ent, weight, Mvec, wnorm, offs_e, csr_e, out);
    user_gather_k<<<(N_USERS * 16 + BLK - 1) / BLK, BLK, 0, stream>>>(
        ent, uemb, lat, disen, offs_u, csr_c, csr_v, out_user);
}

// Round 4
// 406.317 us; speedup vs baseline: 4.9938x; 1.0899x over previous
//
#include <hip/hip_runtime.h>
#include <math.h>

#define N_ENT 200000
#define N_USERS 100000
#define NKEY 300000            // N_ENT + N_USERS unified key space
#define N_FACTORS 4
#define NREL1 25               // N_REL - 1
#define CH 64
#define N_EDGES 1000000
#define NNZ 1000000
#define NREC 2000000           // N_EDGES + NNZ unified records
#define BSHIFT 11
#define NBUCKET 147            // ceil(NKEY / 2048)
#define TILE 2048

// 1 / (2*sqrt(32))
#define SCORE_SCALE 0.08838834764831845f
#define INV_Q14 6.103888176768602e-05f   // 1/16383

__device__ __forceinline__ float red16(float d) {
    d += __shfl_xor(d, 1);
    d += __shfl_xor(d, 2);
    d += __shfl_xor(d, 4);
    d += __shfl_xor(d, 8);
    return d;
}
__device__ __forceinline__ float dot4(float4 a, float4 b) {
    return a.x * b.x + a.y * b.y + a.z * b.z + a.w * b.w;
}

// ---- tiny precompute: Mvec[r] = (W W^T) weight[r]; wnorm[r]; disen[f][c] ----
__global__ void precompute_k(const float* __restrict__ W,
                             const float* __restrict__ weight,
                             const float* __restrict__ datt,
                             float* __restrict__ Mvec,
                             float* __restrict__ wnorm,
                             float* __restrict__ disen) {
    __shared__ float sW[64 * 64];
    __shared__ float sw[NREL1 * 64];
    __shared__ float sWWt[64 * 64];
    int tid = threadIdx.x;
    for (int i = tid; i < 64 * 64; i += 256) sW[i] = W[i];
    for (int i = tid; i < NREL1 * 64; i += 256) sw[i] = weight[i];
    __syncthreads();
    for (int e = tid; e < 64 * 64; e += 256) {
        int i = e >> 6, j = e & 63;
        float s = 0.f;
        for (int k = 0; k < 64; ++k) s += sW[i * 64 + k] * sW[j * 64 + k];
        sWWt[e] = s;
    }
    __syncthreads();
    for (int e = tid; e < NREL1 * 64; e += 256) {
        int r = e >> 6, i = e & 63;
        float s = 0.f;
        for (int j = 0; j < 64; ++j) s += sWWt[i * 64 + j] * sw[r * 64 + j];
        Mvec[e] = s;
    }
    for (int r = tid; r < NREL1; r += 256) {
        float s = 0.f;
        for (int j = 0; j < 64; ++j) { float v = sw[r * 64 + j]; s += v * v; }
        wnorm[r] = s;
    }
    for (int e = tid; e < N_FACTORS * 64; e += 256) {
        int f = e >> 6, c = e & 63;
        float m = -1e30f;
        for (int r = 0; r < NREL1; ++r) m = fmaxf(m, datt[f * NREL1 + r]);
        float ssum = 0.f, acc = 0.f;
        for (int r = 0; r < NREL1; ++r) {
            float p = expf(datt[f * NREL1 + r] - m);
            ssum += p;
            acc += p * sw[r * 64 + c];
        }
        disen[e] = acc / ssum;
    }
}

// ---- unified count over 300k keys ----
__global__ void count2_k(const int* __restrict__ head,
                         const int* __restrict__ rows,
                         unsigned* __restrict__ cnt) {
    int i = blockIdx.x * 256 + threadIdx.x;
    if (i < N_EDGES) atomicAdd(&cnt[head[i]], 1u);
    else if (i < NREC) atomicAdd(&cnt[N_ENT + rows[i - N_EDGES]], 1u);
}

// ---- scan: per-512-block sums ----
__global__ void block_sums512_k(const unsigned* __restrict__ cnt,
                                unsigned* __restrict__ part) {
    int i = blockIdx.x * 512 + threadIdx.x;
    unsigned v = (i < NKEY) ? cnt[i] : 0u;
    for (int o = 32; o; o >>= 1) v += __shfl_down(v, o);
    __shared__ unsigned ws[8];
    if ((threadIdx.x & 63) == 0) ws[threadIdx.x >> 6] = v;
    __syncthreads();
    if (threadIdx.x == 0) {
        unsigned s = 0;
        for (int w = 0; w < 8; ++w) s += ws[w];
        part[blockIdx.x] = s;
    }
}

// ---- scan: single-block exclusive scan of n<=1024 partials ----
__global__ void scan1024_k(unsigned* __restrict__ p, int n) {
    __shared__ unsigned s[1024];
    int tid = threadIdx.x;
    unsigned v = (tid < n) ? p[tid] : 0u;
    s[tid] = v; __syncthreads();
    for (int o = 1; o < 1024; o <<= 1) {
        unsigned t = (tid >= o) ? s[tid - o] : 0u;
        __syncthreads();
        s[tid] += t;
        __syncthreads();
    }
    if (tid < n) p[tid] = s[tid] - v;
}

// ---- scan: emit offsets + cursor init (cnt becomes kcur) ----
__global__ void scan_emit512_k(unsigned* cnt,
                               const unsigned* __restrict__ part,
                               unsigned* __restrict__ offs) {
    __shared__ unsigned s[512];
    int tid = threadIdx.x;
    int i = blockIdx.x * 512 + tid;
    unsigned v = (i < NKEY) ? cnt[i] : 0u;
    s[tid] = v; __syncthreads();
    for (int o = 1; o < 512; o <<= 1) {
        unsigned t = (tid >= o) ? s[tid - o] : 0u;
        __syncthreads();
        s[tid] += t;
        __syncthreads();
    }
    unsigned base = part[blockIdx.x];
    if (i < NKEY) {
        unsigned excl = base + s[tid] - v;
        offs[i] = excl;
        cnt[i] = excl;                    // per-key cursor init
        if (i == NKEY - 1) offs[NKEY] = base + s[tid];
    }
}

// ---- bucket cursor init: gcur[b] = offs[b<<11] ----
__global__ void gcur_init_k(const unsigned* __restrict__ offs,
                            unsigned* __restrict__ gcur) {
    int b = threadIdx.x;
    if (b < NBUCKET) gcur[b] = offs[b << BSHIFT];
}

// ---- stage 1: LDS-binned scatter into bucket-staged arrays ----
__global__ void binfill_k(const int* __restrict__ head, const int* __restrict__ tail,
                          const int* __restrict__ etype,
                          const int* __restrict__ rows, const int* __restrict__ cols,
                          const float* __restrict__ vals,
                          unsigned* __restrict__ gcur,
                          unsigned* __restrict__ skey, unsigned* __restrict__ spay) {
    __shared__ unsigned hist[NBUCKET], base[NBUCKET], gbase[NBUCKET];
    __shared__ unsigned sh[256];
    __shared__ unsigned lkey[TILE], lpay[TILE];
    int tid = threadIdx.x;
    int tile0 = blockIdx.x * TILE;
    int tile_n = min(TILE, NREC - tile0);
    for (int b = tid; b < NBUCKET; b += 256) hist[b] = 0u;
    __syncthreads();
    unsigned key[8], pay[8], rank[8];
    for (int r = 0; r < 8; ++r) {
        int li = r * 256 + tid;
        key[r] = 0xFFFFFFFFu;
        if (li < tile_n) {
            int idx = tile0 + li;
            unsigned k, p;
            if (idx < N_EDGES) {
                k = (unsigned)head[idx];
                p = (unsigned)tail[idx] | ((unsigned)(etype[idx] - 1) << 18);
            } else {
                int j = idx - N_EDGES;
                k = (unsigned)(N_ENT + rows[j]);
                unsigned q = (unsigned)(vals[j] * 16383.f + 0.5f);
                p = (unsigned)cols[j] | (q << 18);
            }
            key[r] = k; pay[r] = p;
            rank[r] = atomicAdd(&hist[k >> BSHIFT], 1u);
        }
    }
    __syncthreads();
    // exclusive scan hist -> base; reserve global bucket space
    unsigned v = (tid < NBUCKET) ? hist[tid] : 0u;
    sh[tid] = v; __syncthreads();
    for (int o = 1; o < 256; o <<= 1) {
        unsigned t = (tid >= o) ? sh[tid - o] : 0u;
        __syncthreads();
        sh[tid] += t;
        __syncthreads();
    }
    if (tid < NBUCKET) {
        base[tid] = sh[tid] - v;
        gbase[tid] = v ? atomicAdd(&gcur[tid], v) : 0u;
    }
    __syncthreads();
    for (int r = 0; r < 8; ++r) {
        if (key[r] != 0xFFFFFFFFu) {
            unsigned b = key[r] >> BSHIFT;
            unsigned pos = base[b] + rank[r];
            lkey[pos] = key[r]; lpay[pos] = pay[r];
        }
    }
    __syncthreads();
    // burst copy: consecutive LDS indices -> consecutive global addresses per run
    for (int i = tid; i < tile_n; i += 256) {
        unsigned k = lkey[i];
        unsigned b = k >> BSHIFT;
        unsigned dst = gbase[b] + ((unsigned)i - base[b]);
        skey[dst] = k; spay[dst] = lpay[i];
    }
}

// ---- stage 2: one block per bucket; scatter within L2-resident window ----
__global__ void binplace_k(const unsigned* __restrict__ offs,
                           unsigned* __restrict__ kcur,
                           const unsigned* __restrict__ skey,
                           const unsigned* __restrict__ spay,
                           unsigned* __restrict__ csr) {
    int b = blockIdx.x;
    unsigned start = offs[b << BSHIFT];
    int endk = (b + 1) << BSHIFT;
    if (endk > NKEY) endk = NKEY;
    unsigned end = offs[endk];
    for (unsigned i = start + threadIdx.x; i < end; i += 256) {
        unsigned k = skey[i];
        unsigned pos = atomicAdd(&kcur[k], 1u);
        csr[pos] = spay[i];
    }
}

// ---- fallback direct fill (if ws too small for staging) ----
__global__ void fill_direct_k(const int* __restrict__ head, const int* __restrict__ tail,
                              const int* __restrict__ etype,
                              const int* __restrict__ rows, const int* __restrict__ cols,
                              const float* __restrict__ vals,
                              unsigned* __restrict__ kcur, unsigned* __restrict__ csr) {
    int i = blockIdx.x * 256 + threadIdx.x;
    if (i < N_EDGES) {
        unsigned p = (unsigned)tail[i] | ((unsigned)(etype[i] - 1) << 18);
        unsigned pos = atomicAdd(&kcur[head[i]], 1u);
        csr[pos] = p;
    } else if (i < NREC) {
        int j = i - N_EDGES;
        unsigned q = (unsigned)(vals[j] * 16383.f + 0.5f);
        unsigned p = (unsigned)cols[j] | (q << 18);
        unsigned pos = atomicAdd(&kcur[N_ENT + rows[j]], 1u);
        csr[pos] = p;
    }
}

// ---- entity gather: per head, two passes over its CSR segment ----
__global__ void ent_gather_k(const float* __restrict__ ent,
                             const float* __restrict__ weight,
                             const float* __restrict__ Mvec,
                             const float* __restrict__ wnorm,
                             const unsigned* __restrict__ offs,
                             const unsigned* __restrict__ csr,
                             float* __restrict__ out) {
    int gid = blockIdx.x * 256 + threadIdx.x;
    int h = gid >> 4;
    int sub = threadIdx.x & 15;
    if (h >= N_ENT) return;
    int beg = offs[h], end = offs[h + 1];
    const float4* e4 = (const float4*)ent;
    float4* o4 = (float4*)out;
    if (beg == end) {
        o4[h * 16 + sub] = make_float4(0.f, 0.f, 0.f, 0.f);
        return;
    }
    float4 hv = e4[h * 16 + sub];
    float dr = 0.f;
    for (int i = beg; i < end; ++i) {
        unsigned p = csr[i];
        int r = p >> 18;
        float d = red16(dot4(hv, ((const float4*)Mvec)[r * 16 + sub]));
        dr += __expf(d * SCORE_SCALE);
    }
    float inv_dr = 1.0f / dr;
    float4 acc = make_float4(0.f, 0.f, 0.f, 0.f);
    float dt = 0.f;
    for (int i = beg; i < end; ++i) {
        unsigned p = csr[i];
        int t = p & 0x3FFFF;
        int r = p >> 18;
        float d1 = red16(dot4(hv, ((const float4*)Mvec)[r * 16 + sub]));
        float er = __expf(d1 * SCORE_SCALE);
        float ra = er * inv_dr;
        float4 tv = e4[t * 16 + sub];
        float d2 = red16(dot4(hv, tv));
        float et = __expf(d2 + ra * ra * wnorm[r]);
        dt += et;
        float4 wv = ((const float4*)weight)[r * 16 + sub];
        acc.x += et * tv.x * wv.x;
        acc.y += et * tv.y * wv.y;
        acc.z += et * tv.z * wv.z;
        acc.w += et * tv.w * wv.w;
    }
    float inv = 1.0f / (dt * (float)(end - beg));
    acc.x *= inv; acc.y *= inv; acc.z *= inv; acc.w *= inv;
    o4[h * 16 + sub] = acc;
}

// ---- user gather + fused softmax scaling epilogue ----
__global__ void user_gather_k(const float* __restrict__ ent,
                              const float* __restrict__ uemb,
                              const float* __restrict__ lat,
                              const float* __restrict__ disen,
                              const unsigned* __restrict__ offs,
                              const unsigned* __restrict__ csr,
                              float* __restrict__ out_user) {
    int gid = blockIdx.x * 256 + threadIdx.x;
    int u = gid >> 4;
    int sub = threadIdx.x & 15;
    if (u >= N_USERS) return;
    int beg = offs[N_ENT + u], end = offs[N_ENT + u + 1];
    const float4* e4 = (const float4*)ent;
    float4 acc = make_float4(0.f, 0.f, 0.f, 0.f);
    for (int i = beg; i < end; ++i) {
        unsigned p = csr[i];
        int c = p & 0x3FFFF;
        float v = (float)(p >> 18) * INV_Q14;
        float4 cv = e4[c * 16 + sub];
        acc.x += v * cv.x; acc.y += v * cv.y; acc.z += v * cv.z; acc.w += v * cv.w;
    }
    float4 uv = ((const float4*)uemb)[u * 16 + sub];
    float d[N_FACTORS];
    for (int f = 0; f < N_FACTORS; ++f)
        d[f] = red16(dot4(uv, ((const float4*)lat)[f * 16 + sub]));
    float m = fmaxf(fmaxf(d[0], d[1]), fmaxf(d[2], d[3]));
    float s = 0.f, p_[N_FACTORS];
    for (int f = 0; f < N_FACTORS; ++f) { p_[f] = __expf(d[f] - m); s += p_[f]; }
    float invs = 1.0f / s;
    float4 g = make_float4(0.f, 0.f, 0.f, 0.f);
    for (int f = 0; f < N_FACTORS; ++f) {
        float w = p_[f] * invs;
        float4 dv = ((const float4*)disen)[f * 16 + sub];
        g.x += w * dv.x; g.y += w * dv.y; g.z += w * dv.z; g.w += w * dv.w;
    }
    acc.x *= (1.0f + g.x); acc.y *= (1.0f + g.y);
    acc.z *= (1.0f + g.z); acc.w *= (1.0f + g.w);
    ((float4*)out_user)[u * 16 + sub] = acc;
}

extern "C" void kernel_launch(void* const* d_in, const int* in_sizes, int n_in,
                              void* d_out, int out_size, void* d_ws, size_t ws_size,
                              hipStream_t stream) {
    (void)in_sizes; (void)n_in; (void)out_size;
    const float* ent    = (const float*)d_in[0];
    const float* uemb   = (const float*)d_in[1];
    const float* lat    = (const float*)d_in[2];
    const int*   eidx   = (const int*)d_in[3];
    const int*   etype  = (const int*)d_in[4];
    const int*   urows  = (const int*)d_in[5];
    const int*   ucols  = (const int*)d_in[6];
    const float* uvals  = (const float*)d_in[7];
    const float* weight = (const float*)d_in[8];
    const float* datt   = (const float*)d_in[9];
    const float* W      = (const float*)d_in[10];

    const int* head = eidx;
    const int* tail = eidx + N_EDGES;
    float* out = (float*)d_out;
    float* out_user = out + (size_t)N_ENT * 64;

    // ws layout (4B words)
    unsigned* cnt   = (unsigned*)d_ws;            // 300000 (becomes kcur)
    unsigned* offs  = cnt + NKEY;                 // 300001
    unsigned* part  = offs + (NKEY + 1);          // 1024 (586 used)
    unsigned* gcur  = part + 1024;                // 160 (147 used)
    float*    Mvec  = (float*)(gcur + 160);       // 1600
    float*    wnorm = Mvec + NREL1 * 64;          // 32
    float*    disen = wnorm + 32;                 // 256
    unsigned* csr   = (unsigned*)(disen + N_FACTORS * 64);  // 2M
    unsigned* skey  = csr + NREC;                 // 2M (binned only)
    unsigned* spay  = skey + NREC;                // 2M (binned only)

    size_t need_binned = (size_t)((skey - cnt) + 2 * NREC) * 4;
    bool binned = ws_size >= need_binned;

    const int BLK = 256;
    const int NBLK512 = (NKEY + 511) / 512;       // 586

    hipMemsetAsync(d_ws, 0, (size_t)NKEY * 4, stream);

    precompute_k<<<1, 256, 0, stream>>>(W, weight, datt, Mvec, wnorm, disen);
    count2_k<<<(NREC + BLK - 1) / BLK, BLK, 0, stream>>>(head, urows, cnt);
    block_sums512_k<<<NBLK512, 512, 0, stream>>>(cnt, part);
    scan1024_k<<<1, 1024, 0, stream>>>(part, NBLK512);
    scan_emit512_k<<<NBLK512, 512, 0, stream>>>(cnt, part, offs);

    if (binned) {
        gcur_init_k<<<1, 256, 0, stream>>>(offs, gcur);
        binfill_k<<<(NREC + TILE - 1) / TILE, BLK, 0, stream>>>(
            head, tail, etype, urows, ucols, uvals, gcur, skey, spay);
        binplace_k<<<NBUCKET, BLK, 0, stream>>>(offs, cnt, skey, spay, csr);
    } else {
        fill_direct_k<<<(NREC + BLK - 1) / BLK, BLK, 0, stream>>>(
            head, tail, etype, urows, ucols, uvals, cnt, csr);
    }

    ent_gather_k<<<(N_ENT * 16 + BLK - 1) / BLK, BLK, 0, stream>>>(
        ent, weight, Mvec, wnorm, offs, csr, out);
    user_gather_k<<<(N_USERS * 16 + BLK - 1) / BLK, BLK, 0, stream>>>(
        ent, uemb, lat, disen, offs, csr, out_user);
}